// Round 8
// baseline (106.097 us; speedup 1.0000x reference)
//
#include <hip/hip_runtime.h>

// Problem: B=16384, X_DIM=1024, K=64, fp32 in/out.
// out[b] = 0.5 * ( sum_k (x_b . V[:,k])^2  -  sum_i x_bi^2 * w_i ),  w_i = sum_k V[i][k]^2
//
// R8: occupancy experiment. Achieved residency was the only variable that ever
// moved cross (~8 waves/CU -> ~50us, ~16 -> ~30us). Target 32 waves/CU:
// 512-thr blocks x 1024 grid = 4 blocks/CU, VGPR <= 64 via launch_bounds(512,8),
// LDS ~35 KB. Single MFMA acc set (dep chains hidden by TLP), direct global x
// reads, trunc-split bf16 repack, LDS-broadcast w.

typedef short short8 __attribute__((ext_vector_type(8)));   // 8 bf16 = 4 VGPRs
typedef float f32x4 __attribute__((ext_vector_type(4)));

constexpr int XD = 1024;
constexpr int KD = 64;

static __device__ __forceinline__ unsigned short f2bf(float f) {
    union { float f; unsigned u; } v; v.f = f;
    unsigned r = v.u + 0x7FFFu + ((v.u >> 16) & 1u);   // RNE
    return (unsigned short)(r >> 16);
}
static __device__ __forceinline__ float bf2f(unsigned short h) {
    union { unsigned u; float f; } v; v.u = ((unsigned)h) << 16;
    return v.f;
}
static __device__ __forceinline__ unsigned fbits(float f) {
    union { float f; unsigned u; } v; v.f = f; return v.u;
}
static __device__ __forceinline__ float bitsf(unsigned u) {
    union { unsigned u; float f; } v; v.u = u; return v.f;
}

// ---- prep: blocks 0..31 build bf16 hi/lo B-fragments (RNE); 32..35 build w ----
// B-fragment layout (mfma_f32_16x16x32_bf16): lane l holds B[k=(l>>4)*8+j][n=l&15]
// ws: bh @ 0 (131072 B) | bl @ 131072 (131072 B) | wc @ 262144 (4096 B)
__global__ void prep_kernel(const float* __restrict__ v,
                            unsigned short* __restrict__ bh,
                            unsigned short* __restrict__ bl,
                            float* __restrict__ wc) {
    if (blockIdx.x < 32) {
        int idx = blockIdx.x * 256 + threadIdx.x;
        int it = idx >> 8;
        int r  = idx & 255;
        int t  = r >> 6;
        int l  = r & 63;
        int q  = l >> 4, m = l & 15;
        int base_i = it * 32 + q * 8;
        int n = t * 16 + m;
        size_t fo = ((size_t)(it * 4 + t) * 64 + l) * 8;
#pragma unroll
        for (int j = 0; j < 8; ++j) {
            float val = v[(size_t)(base_i + j) * KD + n];
            unsigned short h = f2bf(val);
            bh[fo + j] = h;
            bl[fo + j] = f2bf(val - bf2f(h));
        }
    } else {
        int i = (blockIdx.x - 32) * 256 + threadIdx.x;   // 0..1023
        const f32x4* vp = (const f32x4*)(v + (size_t)i * KD);
        f32x4 tv[16];
#pragma unroll
        for (int qq = 0; qq < 16; ++qq) tv[qq] = vp[qq];
        float s = 0.f;
#pragma unroll
        for (int qq = 0; qq < 16; ++qq) {
            s = fmaf(tv[qq].x, tv[qq].x, s); s = fmaf(tv[qq].y, tv[qq].y, s);
            s = fmaf(tv[qq].z, tv[qq].z, s); s = fmaf(tv[qq].w, tv[qq].w, s);
        }
        wc[i] = s;
    }
}

// ---- main: 512 thr / 8 waves; block = 16 rows; wave = 4 i-tiles; 32 waves/CU ----
__global__ __launch_bounds__(512, 8)
void cross_r8(const float* __restrict__ x,
              const unsigned short* __restrict__ bh,
              const unsigned short* __restrict__ bl,
              const float* __restrict__ wc,
              float* __restrict__ out) {
    __shared__ float wlds[XD];             //  4096 B
    __shared__ float comb[7][64][17];      // 30464 B, pitch 17 -> conflict-free
    __shared__ float zb[7][16];            //   448 B      (total ~35 KB -> 4 blk/CU)

    const int tid = threadIdx.x;
    const int l = tid & 63;
    const int w = tid >> 6;            // wave 0..7 = i-eighth (4 tiles)
    const int q = l >> 4, m = l & 15;
    const int row0 = blockIdx.x * 16;

    // stage w (512 thr x float2, coalesced aligned)
    *(float2*)&wlds[tid * 2] = *(const float2*)(wc + tid * 2);
    __syncthreads();

    f32x4 c[4];
#pragma unroll
    for (int t = 0; t < 4; ++t) c[t] = f32x4{0.f, 0.f, 0.f, 0.f};
    float z = 0.f;

    const short8* bhp = (const short8*)bh;
    const short8* blp = (const short8*)bl;
    const float* xrow = x + (size_t)(row0 + m) * XD + q * 8;

#pragma unroll
    for (int ii = 0; ii < 4; ++ii) {
        const int it = w * 4 + ii;
        const size_t fbase = (size_t)(it * 4) * 64 + l;

        f32x4 xa = *(const f32x4*)(xrow + it * 32);
        f32x4 xb = *(const f32x4*)(xrow + it * 32 + 4);

        const float* wp = &wlds[it * 32 + q * 8];
        f32x4 wa = *(const f32x4*)wp, wb = *(const f32x4*)(wp + 4);
        float xs[8] = {xa.x, xa.y, xa.z, xa.w, xb.x, xb.y, xb.z, xb.w};
        z = fmaf(xs[0]*xs[0], wa.x, z); z = fmaf(xs[1]*xs[1], wa.y, z);
        z = fmaf(xs[2]*xs[2], wa.z, z); z = fmaf(xs[3]*xs[3], wa.w, z);
        z = fmaf(xs[4]*xs[4], wb.x, z); z = fmaf(xs[5]*xs[5], wb.y, z);
        z = fmaf(xs[6]*xs[6], wb.z, z); z = fmaf(xs[7]*xs[7], wb.w, z);

        // truncation split + v_perm pack (hi16 pairs; lo = exact residual)
        unsigned ahp[4], alp[4];
#pragma unroll
        for (int jp = 0; jp < 4; ++jp) {
            unsigned u0 = fbits(xs[2 * jp]), u1 = fbits(xs[2 * jp + 1]);
            ahp[jp] = __builtin_amdgcn_perm(u1, u0, 0x07060302u);
            float l0 = xs[2 * jp]     - bitsf(u0 & 0xFFFF0000u);
            float l1 = xs[2 * jp + 1] - bitsf(u1 & 0xFFFF0000u);
            alp[jp] = __builtin_amdgcn_perm(fbits(l1), fbits(l0), 0x07060302u);
        }
        short8 ah, al_;
#pragma unroll
        for (int jp = 0; jp < 4; ++jp) {
            ah[2*jp]   = (short)(ahp[jp] & 0xFFFF); ah[2*jp+1]  = (short)(ahp[jp] >> 16);
            al_[2*jp]  = (short)(alp[jp] & 0xFFFF); al_[2*jp+1] = (short)(alp[jp] >> 16);
        }

        // single acc set: 3 chained MFMAs per t (dep latency hidden by 8 waves/SIMD)
#pragma unroll
        for (int t = 0; t < 4; ++t) {
            short8 vh = bhp[fbase + (size_t)t * 64];
            short8 vl = blp[fbase + (size_t)t * 64];
            c[t] = __builtin_amdgcn_mfma_f32_16x16x32_bf16(ah,  vh, c[t], 0, 0, 0);
            c[t] = __builtin_amdgcn_mfma_f32_16x16x32_bf16(ah,  vl, c[t], 0, 0, 0);
            c[t] = __builtin_amdgcn_mfma_f32_16x16x32_bf16(al_, vh, c[t], 0, 0, 0);
        }
    }

    // z: sum over q-chunks -> full-q partial z for row m (this wave's i-range)
    z += __shfl_xor(z, 16);
    z += __shfl_xor(z, 32);

    // combine partial y across 8 waves (sum BEFORE squaring)
    if (w > 0) {
        const int s = w - 1;
#pragma unroll
        for (int t = 0; t < 4; ++t)
#pragma unroll
            for (int r = 0; r < 4; ++r) comb[s][l][t * 4 + r] = c[t][r];
        if (l < 16) zb[s][l] = z;
    }
    __syncthreads();

    if (w == 0) {
#pragma unroll
        for (int s = 0; s < 7; ++s) {
#pragma unroll
            for (int t = 0; t < 4; ++t)
#pragma unroll
                for (int r = 0; r < 4; ++r) c[t][r] += comb[s][l][t * 4 + r];
            z += zb[s][m];
        }

        // C layout: col = l&15, row = q*4 + reg
        float p[4] = {0.f, 0.f, 0.f, 0.f};
#pragma unroll
        for (int r = 0; r < 4; ++r)
#pragma unroll
            for (int t = 0; t < 4; ++t) p[r] = fmaf(c[t][r], c[t][r], p[r]);
#pragma unroll
        for (int mask = 1; mask < 16; mask <<= 1)
#pragma unroll
            for (int r = 0; r < 4; ++r) p[r] += __shfl_xor(p[r], mask);

        float zrow = __shfl(z, q * 4 + m, 16);
        if (m < 4) out[row0 + q * 4 + m] = 0.5f * (p[m] - zrow);
    }
}

extern "C" void kernel_launch(void* const* d_in, const int* in_sizes, int n_in,
                              void* d_out, int out_size, void* d_ws, size_t ws_size,
                              hipStream_t stream) {
    const float* x = (const float*)d_in[0];      // (16384, 1024) fp32
    const float* v = (const float*)d_in[1];      // (1024, 64) fp32
    float* out = (float*)d_out;                  // (16384, 1) fp32

    unsigned short* bh = (unsigned short*)d_ws;                    // 131072 B
    unsigned short* bl = (unsigned short*)((char*)d_ws + 131072);  // 131072 B
    float* wc = (float*)((char*)d_ws + 262144);                    //   4096 B

    const int B = in_sizes[0] / XD;              // 16384

    hipLaunchKernelGGL(prep_kernel, dim3(36), dim3(256), 0, stream, v, bh, bl, wc);
    hipLaunchKernelGGL(cross_r8, dim3(B / 16), dim3(512), 0, stream,
                       x, bh, bl, wc, out);
}